// Round 2
// baseline (74.806 us; speedup 1.0000x reference)
//
#include <hip/hip_runtime.h>

#define DEVI __device__ __forceinline__

typedef __attribute__((ext_vector_type(8)))  short s16x8;
typedef __attribute__((ext_vector_type(4)))  short s16x4;
typedef __attribute__((ext_vector_type(4)))  float f32x4;
typedef __attribute__((ext_vector_type(16))) float f32x16;

// float -> bf16 (RNE), bit pattern as short
DEVI short f2bf(float f) {
  unsigned u = __builtin_bit_cast(unsigned, f);
  u = u + 0x7fffu + ((u >> 16) & 1u);
  return (short)(u >> 16);
}

// Problem constants
constexpr int TT = 512;   // sequence length
constexpr int CC = 64;    // channels
// workspace element offsets (shorts) for weights
// WqB[3][64][64] | WkB[3][64][64] | WvB[64][64] | WfB[64][64]
// then bf16 tensors q,k,v,attn each 64*512*64

// ---------------------------------------------------------------------------
// Kernel 0: weight repack fp32 -> bf16.  WqB[kk][co][ci] = Wq[co][ci][kk]
// ---------------------------------------------------------------------------
__global__ __launch_bounds__(256) void k_prep(const float* __restrict__ Wq,
                                              const float* __restrict__ Wk,
                                              const float* __restrict__ Wv,
                                              const float* __restrict__ Wf,
                                              short* __restrict__ wsw) {
  int i = blockIdx.x * 256 + threadIdx.x;
  const int total = 12288 + 12288 + 4096 + 4096;
  if (i >= total) return;
  if (i < 12288) {
    int kk = i >> 12, rem = i & 4095;
    wsw[(kk << 12) + rem] = f2bf(Wq[rem * 3 + kk]);
  } else if (i < 24576) {
    int j = i - 12288;
    int kk = j >> 12, rem = j & 4095;
    wsw[12288 + (kk << 12) + rem] = f2bf(Wk[rem * 3 + kk]);
  } else if (i < 28672) {
    int j = i - 24576;
    wsw[24576 + j] = f2bf(Wv[j]);
  } else {
    int j = i - 28672;
    wsw[28672 + j] = f2bf(Wf[j]);
  }
}

// ---------------------------------------------------------------------------
// Kernel 1: Q/K causal conv (as 3 shifted GEMMs) + V 1x1 conv, all via
// mfma_f32_32x32x16_bf16.  Block = (bn, t-tile of 128 rows), 256 threads.
// X rows staged in LDS as bf16, 128B rows, XOR swizzle byte ^= ((row&7)<<4).
// ---------------------------------------------------------------------------
__global__ __launch_bounds__(256) void k_qkv(const float* __restrict__ values,
                                             const float* __restrict__ keys,
                                             const float* __restrict__ query,
                                             const float* __restrict__ bq,
                                             const float* __restrict__ bk,
                                             const short* __restrict__ wsw,
                                             short* __restrict__ qg,
                                             short* __restrict__ kg,
                                             short* __restrict__ vg) {
  __shared__ __align__(16) short lq[130 * 64];
  __shared__ __align__(16) short lk[130 * 64];
  __shared__ __align__(16) short lv[128 * 64];
  const int tid = threadIdx.x;
  const int bn = blockIdx.x >> 2, ttile = blockIdx.x & 3;
  const int t0 = ttile * 128;
  const size_t xbase = (size_t)bn * TT * CC;

  // stage query/keys rows [t0-2, t0+128)  (zeros for t<0)
  for (int s = tid; s < 130 * 8; s += 256) {
    int row = s >> 3, c8 = s & 7;
    int t = t0 - 2 + row;
    s16x8 rq, rk;
    if (t >= 0) {
      const float* pq = query + xbase + (size_t)t * 64 + c8 * 8;
      const float* pk = keys + xbase + (size_t)t * 64 + c8 * 8;
#pragma unroll
      for (int j = 0; j < 8; ++j) { rq[j] = f2bf(pq[j]); rk[j] = f2bf(pk[j]); }
    } else {
#pragma unroll
      for (int j = 0; j < 8; ++j) { rq[j] = 0; rk[j] = 0; }
    }
    int byte = row * 128 + ((c8 * 16) ^ ((row & 7) << 4));
    *(s16x8*)((char*)lq + byte) = rq;
    *(s16x8*)((char*)lk + byte) = rk;
  }
  // stage values rows [t0, t0+128)
  for (int s = tid; s < 128 * 8; s += 256) {
    int row = s >> 3, c8 = s & 7;
    const float* pv = values + xbase + (size_t)(t0 + row) * 64 + c8 * 8;
    s16x8 rv;
#pragma unroll
    for (int j = 0; j < 8; ++j) rv[j] = f2bf(pv[j]);
    int byte = row * 128 + ((c8 * 16) ^ ((row & 7) << 4));
    *(s16x8*)((char*)lv + byte) = rv;
  }
  __syncthreads();

  const int lane = tid & 63, w = tid >> 6;
  const int r = lane & 31, hl = lane >> 5;
  const short* wqb = wsw;            // [3][64][64]
  const short* wkb = wsw + 12288;    // [3][64][64]
  const short* wvb = wsw + 24576;    // [64][64]

  // 24 output tiles: tensor(3) x mt(4) x nt(2); wave-strided
  for (int job = w; job < 24; job += 4) {
    int tsr = job >> 3, tj = job & 7, mt = tj >> 1, nt = tj & 1;
    f32x16 acc;
#pragma unroll
    for (int i = 0; i < 16; ++i) acc[i] = 0.f;

    if (tsr < 2) {
      const short* lsrc = tsr ? lk : lq;
      const short* wb = tsr ? wkb : wqb;
#pragma unroll
      for (int kk = 0; kk < 3; ++kk) {
#pragma unroll
        for (int c4 = 0; c4 < 4; ++c4) {
          int lrow = mt * 32 + r + kk;
          int abyte = lrow * 128 + (((c4 * 16 + hl * 8) * 2) ^ ((lrow & 7) << 4));
          s16x8 af = *(const s16x8*)((const char*)lsrc + abyte);
          s16x8 bfr = *(const s16x8*)(wb + kk * 4096 + (nt * 32 + r) * 64 + c4 * 16 + hl * 8);
          acc = __builtin_amdgcn_mfma_f32_32x32x16_bf16(af, bfr, acc, 0, 0, 0);
        }
      }
    } else {
#pragma unroll
      for (int c4 = 0; c4 < 4; ++c4) {
        int lrow = mt * 32 + r;
        int abyte = lrow * 128 + (((c4 * 16 + hl * 8) * 2) ^ ((lrow & 7) << 4));
        s16x8 af = *(const s16x8*)((const char*)lv + abyte);
        s16x8 bfr = *(const s16x8*)(wvb + (nt * 32 + r) * 64 + c4 * 16 + hl * 8);
        acc = __builtin_amdgcn_mfma_f32_32x32x16_bf16(af, bfr, acc, 0, 0, 0);
      }
    }
    int co = nt * 32 + r;
    float bias = (tsr == 0) ? bq[co] : (tsr == 1) ? bk[co] : 0.f;
    short* dst = (tsr == 0) ? qg : (tsr == 1) ? kg : vg;
#pragma unroll
    for (int reg = 0; reg < 16; ++reg) {
      int trow = mt * 32 + (reg & 3) + 8 * (reg >> 2) + 4 * hl;
      dst[((size_t)bn * TT + (t0 + trow)) * 64 + co] = f2bf(acc[reg] + bias);
    }
  }
}

// ---------------------------------------------------------------------------
// Kernel 2: attention per (bn, h).  Swapped QK^T (mfma(K,Q) -> lane owns one
// q column), two-pass softmax, PV via 16x16x32 with P LDS round-trip.
// Q/K LDS: FRAGMENT-MAJOR layout — per 32-row tile nt, lane l's 16B frag at
// byte nt*1024 + l*16, i.e. byte(row,hh) = (row>>5)*1024 + (row&31)*16 + hh*512.
// Same layout serves A-operand (K) and B-operand (Q): both have
// m/n = lane&31, k = (lane>>5)*8 + j.  All frag reads are linear ds_read_b128.
// V LDS linear [512][16].
// ---------------------------------------------------------------------------
__global__ __launch_bounds__(256) void k_attn(const short* __restrict__ qg,
                                              const short* __restrict__ kg,
                                              const short* __restrict__ vg,
                                              short* __restrict__ ag) {
  __shared__ __align__(16) short Ql[512 * 16];
  __shared__ __align__(16) short Kl[512 * 16];
  __shared__ __align__(16) short Vl[512 * 16];
  __shared__ __align__(16) short Pl[4][32 * 40];  // per-wave, rows padded to 40
  __shared__ float Sums[4][32];
  const int tid = threadIdx.x;
  const int bn = blockIdx.x >> 2, h = blockIdx.x & 3;

  for (int s = tid; s < 3 * 1024; s += 256) {
    int tsr = s >> 10, s2 = s & 1023, row = s2 >> 1, hh = s2 & 1;
    const short* src = (tsr == 0 ? qg : tsr == 1 ? kg : vg) +
                       ((size_t)bn * TT + row) * 64 + h * 16 + hh * 8;
    s16x8 v = *(const s16x8*)src;
    char* dstb;
    int byte;
    if (tsr == 2) { dstb = (char*)Vl; byte = row * 32 + hh * 16; }
    else {
      dstb = (tsr == 0) ? (char*)Ql : (char*)Kl;
      byte = (row >> 5) * 1024 + (row & 31) * 16 + hh * 512;  // frag-major
    }
    *(s16x8*)(dstb + byte) = v;
  }
  __syncthreads();

  const int lane = tid & 63, w = tid >> 6;
  const int r = lane & 31, hl = lane >> 5;
  const int d = lane & 15, g = lane >> 4;

  // cache K fragments (A-operand of 32x32x16): kf[nt] = K[nt*32 + r][hl*8 + j]
  s16x8 kf[16];
#pragma unroll
  for (int nt = 0; nt < 16; ++nt)
    kf[nt] = *(const s16x8*)((const char*)Kl + nt * 1024 + lane * 16);

  // cache V fragments (B-operand of 16x16x32): vf[nt][j] = V[nt*32 + g*8 + j][d]
  s16x8 vf[16];
#pragma unroll
  for (int nt = 0; nt < 16; ++nt) {
#pragma unroll
    for (int j = 0; j < 8; ++j) vf[nt][j] = Vl[(nt * 32 + g * 8 + j) * 16 + d];
  }

  f32x16 z;
#pragma unroll
  for (int i = 0; i < 16; ++i) z[i] = 0.f;
  const float SCL = 0.18033688011112042f;  // log2(e)/8

  for (int mt = w; mt < 16; mt += 4) {
    s16x8 qf = *(const s16x8*)((const char*)Ql + mt * 1024 + lane * 16);

    // pass A: row max (raw energies).  lane owns q-col = r; regs are k rows.
    float mx = -3.0e38f;
#pragma unroll
    for (int nt = 0; nt < 16; ++nt) {
      f32x16 s = __builtin_amdgcn_mfma_f32_32x32x16_bf16(kf[nt], qf, z, 0, 0, 0);
#pragma unroll
      for (int i = 0; i < 16; ++i) mx = fmaxf(mx, s[i]);
    }
    mx = fmaxf(mx, __shfl_xor(mx, 32));

    // pass B: exp, sum, P pack->LDS, PV accumulate
    float sum = 0.f;
    f32x4 o1, o2;
#pragma unroll
    for (int i = 0; i < 4; ++i) { o1[i] = 0.f; o2[i] = 0.f; }
#pragma unroll
    for (int nt = 0; nt < 16; ++nt) {
      f32x16 s = __builtin_amdgcn_mfma_f32_32x32x16_bf16(kf[nt], qf, z, 0, 0, 0);
      float p[16];
#pragma unroll
      for (int i = 0; i < 16; ++i) {
        p[i] = exp2f((s[i] - mx) * SCL);
        sum += p[i];
      }
      // reg R holds k_local = (R&3) + 8*(R>>2) + 4*hl ; write P[q=r][k_local]
#pragma unroll
      for (int g2 = 0; g2 < 4; ++g2) {
        s16x4 pk4;
        pk4[0] = f2bf(p[4 * g2 + 0]);
        pk4[1] = f2bf(p[4 * g2 + 1]);
        pk4[2] = f2bf(p[4 * g2 + 2]);
        pk4[3] = f2bf(p[4 * g2 + 3]);
        *(s16x4*)(&Pl[w][r * 40 + g2 * 8 + hl * 4]) = pk4;
      }
      // read back as 16x16x32 A-frags (two 16-row halves)
      s16x8 pa = *(const s16x8*)(&Pl[w][d * 40 + g * 8]);
      s16x8 pb = *(const s16x8*)(&Pl[w][(16 + d) * 40 + g * 8]);
      o1 = __builtin_amdgcn_mfma_f32_16x16x32_bf16(pa, vf[nt], o1, 0, 0, 0);
      o2 = __builtin_amdgcn_mfma_f32_16x16x32_bf16(pb, vf[nt], o2, 0, 0, 0);
    }
    sum += __shfl_xor(sum, 32);
    Sums[w][r] = sum;
#pragma unroll
    for (int reg = 0; reg < 4; ++reg) {
      float s1 = Sums[w][g * 4 + reg];
      float s2 = Sums[w][16 + g * 4 + reg];
      int q1 = mt * 32 + g * 4 + reg;
      int q2 = q1 + 16;
      ag[((size_t)bn * TT + q1) * 64 + h * 16 + d] = f2bf(o1[reg] / s1);
      ag[((size_t)bn * TT + q2) * 64 + h * 16 + d] = f2bf(o2[reg] / s2);
    }
  }
}

// ---------------------------------------------------------------------------
// Kernel 3: final linear out = attn @ Wf^T + bf (fp32 out)
// ---------------------------------------------------------------------------
__global__ __launch_bounds__(256) void k_out(const short* __restrict__ ag,
                                             const short* __restrict__ wfb,
                                             const float* __restrict__ bfv,
                                             float* __restrict__ out) {
  __shared__ __align__(16) short la[128 * 64];
  const int tid = threadIdx.x;
  const int bn = blockIdx.x >> 2, ttile = blockIdx.x & 3;
  const int t0 = ttile * 128;
  for (int s = tid; s < 128 * 8; s += 256) {
    int row = s >> 3, c8 = s & 7;
    s16x8 v = *(const s16x8*)(ag + ((size_t)bn * TT + t0 + row) * 64 + c8 * 8);
    int byte = row * 128 + ((c8 * 16) ^ ((row & 7) << 4));
    *(s16x8*)((char*)la + byte) = v;
  }
  __syncthreads();
  const int lane = tid & 63, w = tid >> 6;
  const int r = lane & 31, hl = lane >> 5;
  for (int job = w; job < 8; job += 4) {
    int mt = job >> 1, nt = job & 1;
    f32x16 acc;
#pragma unroll
    for (int i = 0; i < 16; ++i) acc[i] = 0.f;
#pragma unroll
    for (int c4 = 0; c4 < 4; ++c4) {
      int lrow = mt * 32 + r;
      int abyte = lrow * 128 + (((c4 * 16 + hl * 8) * 2) ^ ((lrow & 7) << 4));
      s16x8 af = *(const s16x8*)((const char*)la + abyte);
      s16x8 bfr = *(const s16x8*)(wfb + (nt * 32 + r) * 64 + c4 * 16 + hl * 8);
      acc = __builtin_amdgcn_mfma_f32_32x32x16_bf16(af, bfr, acc, 0, 0, 0);
    }
    int co = nt * 32 + r;
    float bias = bfv[co];
#pragma unroll
    for (int reg = 0; reg < 16; ++reg) {
      int trow = mt * 32 + (reg & 3) + 8 * (reg >> 2) + 4 * hl;
      out[((size_t)bn * TT + t0 + trow) * 64 + co] = acc[reg] + bias;
    }
  }
}

// ---------------------------------------------------------------------------
extern "C" void kernel_launch(void* const* d_in, const int* in_sizes, int n_in,
                              void* d_out, int out_size, void* d_ws, size_t ws_size,
                              hipStream_t stream) {
  const float* values = (const float*)d_in[0];
  const float* keys = (const float*)d_in[1];
  const float* query = (const float*)d_in[2];
  const float* Wq = (const float*)d_in[3];
  const float* bq = (const float*)d_in[4];
  const float* Wk = (const float*)d_in[5];
  const float* bk = (const float*)d_in[6];
  const float* Wv = (const float*)d_in[7];
  const float* Wf = (const float*)d_in[8];
  const float* bfv = (const float*)d_in[9];
  float* out = (float*)d_out;

  char* ws = (char*)d_ws;
  short* wsw = (short*)ws;                              // 32768 shorts = 64 KiB
  short* qg = (short*)(ws + (1 << 16));                 // 4 MiB each
  short* kg = (short*)(ws + (1 << 16) + (1 << 22));
  short* vg = (short*)(ws + (1 << 16) + 2 * (1 << 22));
  short* ag = (short*)(ws + (1 << 16) + 3 * (size_t)(1 << 22));

  hipLaunchKernelGGL(k_prep, dim3(128), dim3(256), 0, stream, Wq, Wk, Wv, Wf, wsw);
  hipLaunchKernelGGL(k_qkv, dim3(256), dim3(256), 0, stream,
                     values, keys, query, bq, bk, wsw, qg, kg, vg);
  hipLaunchKernelGGL(k_attn, dim3(256), dim3(256), 0, stream, qg, kg, vg, ag);
  hipLaunchKernelGGL(k_out, dim3(256), dim3(256), 0, stream, ag, wsw + 28672, bfv, out);
}

// Round 3
// 53.334 us; speedup vs baseline: 1.4026x; 1.4026x over previous
//
#include <hip/hip_runtime.h>

#define DEVI __device__ __forceinline__

typedef __attribute__((ext_vector_type(8)))  short s16x8;
typedef __attribute__((ext_vector_type(4)))  short s16x4;
typedef __attribute__((ext_vector_type(4)))  float f32x4;
typedef __attribute__((ext_vector_type(16))) float f32x16;
typedef __attribute__((ext_vector_type(2)))  unsigned int u32x2;

// float -> bf16 (RNE), bit pattern as short
DEVI short f2bf(float f) {
  unsigned u = __builtin_bit_cast(unsigned, f);
  u = u + 0x7fffu + ((u >> 16) & 1u);
  return (short)(u >> 16);
}

// two floats -> packed bf16 pair via HW cvt (RNE)
DEVI unsigned cvtpk(float lo, float hi) {
  unsigned r;
  asm("v_cvt_pk_bf16_f32 %0, %1, %2" : "=v"(r) : "v"(lo), "v"(hi));
  return r;
}

constexpr int TT = 512;
constexpr int CC = 64;
constexpr float SCLQ = 0.18033688011112042f;  // log2(e)/8, folded into Q

// ---------------------------------------------------------------------------
// Kernel 0: weight repack fp32 -> bf16.  WqB[kk][co][ci] = Wq[co][ci][kk]
// ---------------------------------------------------------------------------
__global__ __launch_bounds__(256) void k_prep(const float* __restrict__ Wq,
                                              const float* __restrict__ Wk,
                                              const float* __restrict__ Wv,
                                              const float* __restrict__ Wf,
                                              short* __restrict__ wsw) {
  int i = blockIdx.x * 256 + threadIdx.x;
  const int total = 12288 + 12288 + 4096 + 4096;
  if (i >= total) return;
  if (i < 12288) {
    int kk = i >> 12, rem = i & 4095;
    wsw[(kk << 12) + rem] = f2bf(Wq[rem * 3 + kk]);
  } else if (i < 24576) {
    int j = i - 12288;
    int kk = j >> 12, rem = j & 4095;
    wsw[12288 + (kk << 12) + rem] = f2bf(Wk[rem * 3 + kk]);
  } else if (i < 28672) {
    int j = i - 24576;
    wsw[24576 + j] = f2bf(Wv[j]);
  } else {
    int j = i - 28672;
    wsw[28672 + j] = f2bf(Wf[j]);
  }
}

// ---------------------------------------------------------------------------
// Kernel 1: Q/K causal conv (3 shifted GEMMs) + V 1x1 conv via
// mfma_f32_32x32x16_bf16.  Q is pre-scaled by log2(e)/8.  V is written
// TRANSPOSED: vgT[bn][c][t]  (via LDS transpose + coalesced copy-out).
// ---------------------------------------------------------------------------
__global__ __launch_bounds__(256) void k_qkv(const float* __restrict__ values,
                                             const float* __restrict__ keys,
                                             const float* __restrict__ query,
                                             const float* __restrict__ bq,
                                             const float* __restrict__ bk,
                                             const short* __restrict__ wsw,
                                             short* __restrict__ qg,
                                             short* __restrict__ kg,
                                             short* __restrict__ vgT) {
  __shared__ __align__(16) short lq[130 * 64];
  __shared__ __align__(16) short lk[130 * 64];
  __shared__ __align__(16) short lv[128 * 64];
  __shared__ __align__(16) short lvT[64 * 128];  // [co][t_local], XOR swizzled
  const int tid = threadIdx.x;
  const int bn = blockIdx.x >> 2, ttile = blockIdx.x & 3;
  const int t0 = ttile * 128;
  const size_t xbase = (size_t)bn * TT * CC;

  // stage query/keys rows [t0-2, t0+128)  (zeros for t<0) — float4 loads
  for (int s = tid; s < 130 * 8; s += 256) {
    int row = s >> 3, c8 = s & 7;
    int t = t0 - 2 + row;
    s16x8 rq, rk;
    if (t >= 0) {
      const float4 qa = *(const float4*)(query + xbase + (size_t)t * 64 + c8 * 8);
      const float4 qb = *(const float4*)(query + xbase + (size_t)t * 64 + c8 * 8 + 4);
      const float4 ka = *(const float4*)(keys + xbase + (size_t)t * 64 + c8 * 8);
      const float4 kb = *(const float4*)(keys + xbase + (size_t)t * 64 + c8 * 8 + 4);
      rq[0] = f2bf(qa.x); rq[1] = f2bf(qa.y); rq[2] = f2bf(qa.z); rq[3] = f2bf(qa.w);
      rq[4] = f2bf(qb.x); rq[5] = f2bf(qb.y); rq[6] = f2bf(qb.z); rq[7] = f2bf(qb.w);
      rk[0] = f2bf(ka.x); rk[1] = f2bf(ka.y); rk[2] = f2bf(ka.z); rk[3] = f2bf(ka.w);
      rk[4] = f2bf(kb.x); rk[5] = f2bf(kb.y); rk[6] = f2bf(kb.z); rk[7] = f2bf(kb.w);
    } else {
#pragma unroll
      for (int j = 0; j < 8; ++j) { rq[j] = 0; rk[j] = 0; }
    }
    int byte = row * 128 + ((c8 * 16) ^ ((row & 7) << 4));
    *(s16x8*)((char*)lq + byte) = rq;
    *(s16x8*)((char*)lk + byte) = rk;
  }
  // stage values rows [t0, t0+128)
  for (int s = tid; s < 128 * 8; s += 256) {
    int row = s >> 3, c8 = s & 7;
    const float4 va = *(const float4*)(values + xbase + (size_t)(t0 + row) * 64 + c8 * 8);
    const float4 vb = *(const float4*)(values + xbase + (size_t)(t0 + row) * 64 + c8 * 8 + 4);
    s16x8 rv;
    rv[0] = f2bf(va.x); rv[1] = f2bf(va.y); rv[2] = f2bf(va.z); rv[3] = f2bf(va.w);
    rv[4] = f2bf(vb.x); rv[5] = f2bf(vb.y); rv[6] = f2bf(vb.z); rv[7] = f2bf(vb.w);
    int byte = row * 128 + ((c8 * 16) ^ ((row & 7) << 4));
    *(s16x8*)((char*)lv + byte) = rv;
  }
  __syncthreads();

  const int lane = tid & 63, w = tid >> 6;
  const int r = lane & 31, hl = lane >> 5;
  const short* wqb = wsw;            // [3][64][64]
  const short* wkb = wsw + 12288;    // [3][64][64]
  const short* wvb = wsw + 24576;    // [64][64]

  // 24 tiles: tensor(3: Q,K,V) x mt(4) x nt(2); wave-strided
  for (int job = w; job < 24; job += 4) {
    int tsr = job >> 3, tj = job & 7, mt = tj >> 1, nt = tj & 1;
    f32x16 acc;
#pragma unroll
    for (int i = 0; i < 16; ++i) acc[i] = 0.f;

    if (tsr < 2) {
      const short* lsrc = tsr ? lk : lq;
      const short* wb = tsr ? wkb : wqb;
#pragma unroll
      for (int kk = 0; kk < 3; ++kk) {
#pragma unroll
        for (int c4 = 0; c4 < 4; ++c4) {
          int lrow = mt * 32 + r + kk;
          int abyte = lrow * 128 + (((c4 * 16 + hl * 8) * 2) ^ ((lrow & 7) << 4));
          s16x8 af = *(const s16x8*)((const char*)lsrc + abyte);
          s16x8 bfr = *(const s16x8*)(wb + kk * 4096 + (nt * 32 + r) * 64 + c4 * 16 + hl * 8);
          acc = __builtin_amdgcn_mfma_f32_32x32x16_bf16(af, bfr, acc, 0, 0, 0);
        }
      }
    } else {
#pragma unroll
      for (int c4 = 0; c4 < 4; ++c4) {
        int lrow = mt * 32 + r;
        int abyte = lrow * 128 + (((c4 * 16 + hl * 8) * 2) ^ ((lrow & 7) << 4));
        s16x8 af = *(const s16x8*)((const char*)lv + abyte);
        s16x8 bfr = *(const s16x8*)(wvb + (nt * 32 + r) * 64 + c4 * 16 + hl * 8);
        acc = __builtin_amdgcn_mfma_f32_32x32x16_bf16(af, bfr, acc, 0, 0, 0);
      }
    }
    int co = nt * 32 + r;
    if (tsr == 2) {
      // V: write to transposed LDS tile (XOR-swizzled, 8B chunks)
#pragma unroll
      for (int g2 = 0; g2 < 4; ++g2) {
        int tl = mt * 32 + g2 * 8 + hl * 4;   // 4 consecutive t
        s16x4 pk;
        pk[0] = f2bf(acc[g2 * 4 + 0]);
        pk[1] = f2bf(acc[g2 * 4 + 1]);
        pk[2] = f2bf(acc[g2 * 4 + 2]);
        pk[3] = f2bf(acc[g2 * 4 + 3]);
        *(s16x4*)(lvT + co * 128 + (tl ^ ((co & 15) << 2))) = pk;
      }
    } else {
      float bias = tsr ? bk[co] : bq[co];
      float scl = tsr ? 1.f : SCLQ;
      short* dst = tsr ? kg : qg;
#pragma unroll
      for (int reg = 0; reg < 16; ++reg) {
        int trow = mt * 32 + (reg & 3) + 8 * (reg >> 2) + 4 * hl;
        dst[((size_t)bn * TT + (t0 + trow)) * 64 + co] = f2bf((acc[reg] + bias) * scl);
      }
    }
  }
  __syncthreads();
  // coalesced copy-out: vgT[bn][co][t0 + t]
#pragma unroll
  for (int i = 0; i < 8; ++i) {
    int chunk = tid + 256 * i;          // 2048 chunks of 4 shorts
    int co = chunk >> 5, tc = chunk & 31;
    s16x4 v4 = *(const s16x4*)(lvT + co * 128 + ((tc * 4) ^ ((co & 15) << 2)));
    *(s16x4*)(vgT + ((size_t)bn * 64 + co) * TT + t0 + tc * 4) = v4;
  }
}

// ---------------------------------------------------------------------------
// Kernel 2: attention.  Grid 1024 = (bn, h, qquarter); 4 waves, 1 mt/wave.
// One-pass no-max softmax: p = exp2(S) directly (Q pre-scaled by log2e/8).
// K staged in LDS fragment-major (linear ds_read_b128); V fragments read
// straight from L2 (vgT is t-contiguous per channel); P via small LDS
// round-trip; Q fragment straight from global.
// ---------------------------------------------------------------------------
__global__ __launch_bounds__(256, 4) void k_attn(const short* __restrict__ qg,
                                                 const short* __restrict__ kg,
                                                 const short* __restrict__ vgT,
                                                 short* __restrict__ ag) {
  __shared__ __align__(16) short Kl[512 * 16];   // frag-major: tile nt at nt*512, lane*8
  __shared__ __align__(16) short Pl[4][32 * 40]; // per-wave P tile, stride 40
  __shared__ float Sums[4][32];
  const int tid = threadIdx.x;
  // bijective XCD swizzle: all 16 (h,qq) blocks of one bn land on one XCD
  const int b = (blockIdx.x & 7) * 128 + (blockIdx.x >> 3);
  const int bn = b >> 4, h = (b >> 2) & 3, qq = b & 3;
  const int lane = tid & 63, w = tid >> 6;
  const int r = lane & 31, hl = lane >> 5;
  const int d = lane & 15, g = lane >> 4;

  // stage K slice (512 x 16) into fragment-major LDS
  const short* kslice = kg + (size_t)bn * TT * CC + h * 16;
  for (int s = tid; s < 1024; s += 256) {
    int row = s >> 1, hh = s & 1;
    s16x8 kv = *(const s16x8*)(kslice + (size_t)row * CC + hh * 8);
    *(s16x8*)(Kl + (row >> 5) * 512 + (row & 31) * 8 + hh * 256) = kv;
  }

  const int mt = qq * 4 + w;
  s16x8 qf = *(const s16x8*)(qg + ((size_t)bn * TT + mt * 32 + r) * CC + h * 16 + hl * 8);
  const short* vbase = vgT + ((size_t)bn * 64 + h * 16 + d) * TT + g * 8;
  short* plw = Pl[w];

  __syncthreads();

  f32x16 z;
#pragma unroll
  for (int i = 0; i < 16; ++i) z[i] = 0.f;
  float sum = 0.f;
  f32x4 o1, o2;
#pragma unroll
  for (int i = 0; i < 4; ++i) { o1[i] = 0.f; o2[i] = 0.f; }

#pragma unroll
  for (int nt = 0; nt < 16; ++nt) {
    s16x8 kf = *(const s16x8*)(Kl + nt * 512 + lane * 8);
    s16x8 vf = *(const s16x8*)(vbase + nt * 32);
    f32x16 s = __builtin_amdgcn_mfma_f32_32x32x16_bf16(kf, qf, z, 0, 0, 0);
    float p[16];
#pragma unroll
    for (int i = 0; i < 16; ++i) {
      p[i] = exp2f(s[i]);
      sum += p[i];
    }
    // reg R holds k_local = (R&3) + 8*(R>>2) + 4*hl ; write P[q=r][k_local]
#pragma unroll
    for (int g2 = 0; g2 < 4; ++g2) {
      u32x2 pk;
      pk[0] = cvtpk(p[4 * g2 + 0], p[4 * g2 + 1]);
      pk[1] = cvtpk(p[4 * g2 + 2], p[4 * g2 + 3]);
      *(u32x2*)(plw + r * 40 + g2 * 8 + hl * 4) = pk;
    }
    s16x8 pa = *(const s16x8*)(plw + d * 40 + g * 8);
    s16x8 pb = *(const s16x8*)(plw + (16 + d) * 40 + g * 8);
    o1 = __builtin_amdgcn_mfma_f32_16x16x32_bf16(pa, vf, o1, 0, 0, 0);
    o2 = __builtin_amdgcn_mfma_f32_16x16x32_bf16(pb, vf, o2, 0, 0, 0);
  }
  sum += __shfl_xor(sum, 32);
  Sums[w][r] = sum;
#pragma unroll
  for (int reg = 0; reg < 4; ++reg) {
    float i1 = __builtin_amdgcn_rcpf(Sums[w][g * 4 + reg]);
    float i2 = __builtin_amdgcn_rcpf(Sums[w][16 + g * 4 + reg]);
    int q1 = mt * 32 + g * 4 + reg;
    int q2 = q1 + 16;
    ag[((size_t)bn * TT + q1) * CC + h * 16 + d] = f2bf(o1[reg] * i1);
    ag[((size_t)bn * TT + q2) * CC + h * 16 + d] = f2bf(o2[reg] * i2);
  }
}

// ---------------------------------------------------------------------------
// Kernel 3: final linear out = attn @ Wf^T + bf (fp32 out)
// ---------------------------------------------------------------------------
__global__ __launch_bounds__(256) void k_out(const short* __restrict__ ag,
                                             const short* __restrict__ wfb,
                                             const float* __restrict__ bfv,
                                             float* __restrict__ out) {
  __shared__ __align__(16) short la[128 * 64];
  const int tid = threadIdx.x;
  const int bn = blockIdx.x >> 2, ttile = blockIdx.x & 3;
  const int t0 = ttile * 128;
  for (int s = tid; s < 128 * 8; s += 256) {
    int row = s >> 3, c8 = s & 7;
    s16x8 v = *(const s16x8*)(ag + ((size_t)bn * TT + t0 + row) * 64 + c8 * 8);
    int byte = row * 128 + ((c8 * 16) ^ ((row & 7) << 4));
    *(s16x8*)((char*)la + byte) = v;
  }
  __syncthreads();
  const int lane = tid & 63, w = tid >> 6;
  const int r = lane & 31, hl = lane >> 5;
  for (int job = w; job < 8; job += 4) {
    int mt = job >> 1, nt = job & 1;
    f32x16 acc;
#pragma unroll
    for (int i = 0; i < 16; ++i) acc[i] = 0.f;
#pragma unroll
    for (int c4 = 0; c4 < 4; ++c4) {
      int lrow = mt * 32 + r;
      int abyte = lrow * 128 + (((c4 * 16 + hl * 8) * 2) ^ ((lrow & 7) << 4));
      s16x8 af = *(const s16x8*)((const char*)la + abyte);
      s16x8 bfr = *(const s16x8*)(wfb + (nt * 32 + r) * 64 + c4 * 16 + hl * 8);
      acc = __builtin_amdgcn_mfma_f32_32x32x16_bf16(af, bfr, acc, 0, 0, 0);
    }
    int co = nt * 32 + r;
    float bias = bfv[co];
#pragma unroll
    for (int reg = 0; reg < 16; ++reg) {
      int trow = mt * 32 + (reg & 3) + 8 * (reg >> 2) + 4 * hl;
      out[((size_t)bn * TT + t0 + trow) * 64 + co] = acc[reg] + bias;
    }
  }
}

// ---------------------------------------------------------------------------
extern "C" void kernel_launch(void* const* d_in, const int* in_sizes, int n_in,
                              void* d_out, int out_size, void* d_ws, size_t ws_size,
                              hipStream_t stream) {
  const float* values = (const float*)d_in[0];
  const float* keys = (const float*)d_in[1];
  const float* query = (const float*)d_in[2];
  const float* Wq = (const float*)d_in[3];
  const float* bq = (const float*)d_in[4];
  const float* Wk = (const float*)d_in[5];
  const float* bk = (const float*)d_in[6];
  const float* Wv = (const float*)d_in[7];
  const float* Wf = (const float*)d_in[8];
  const float* bfv = (const float*)d_in[9];
  float* out = (float*)d_out;

  char* ws = (char*)d_ws;
  short* wsw = (short*)ws;                              // 64 KiB weights
  short* qg = (short*)(ws + (1 << 16));                 // 4 MiB each
  short* kg = (short*)(ws + (1 << 16) + (1 << 22));
  short* vgT = (short*)(ws + (1 << 16) + 2 * (1 << 22));
  short* ag = (short*)(ws + (1 << 16) + 3 * (size_t)(1 << 22));

  hipLaunchKernelGGL(k_prep, dim3(128), dim3(256), 0, stream, Wq, Wk, Wv, Wf, wsw);
  hipLaunchKernelGGL(k_qkv, dim3(256), dim3(256), 0, stream,
                     values, keys, query, bq, bk, wsw, qg, kg, vgT);
  hipLaunchKernelGGL(k_attn, dim3(1024), dim3(256), 0, stream, qg, kg, vgT, ag);
  hipLaunchKernelGGL(k_out, dim3(256), dim3(256), 0, stream, ag, wsw + 28672, bfv, out);
}